// Round 23
// baseline (23503.241 us; speedup 1.0000x reference)
//
#include <hip/hip_runtime.h>
#include <math.h>

#define BB 32
#define TENC 200
#define NMELS 80
#define TMELS 400
#define STEPS 200
#define MEM 256
#define PRE1N 256
#define PRE2N 128
#define AD 128
#define DK 21
#define DF 8
#define SK 21
#define SF 8
#define PL 11
#define BLK 1024

// ushort offsets (kk-major quarter packs):
#define QW1 0u         // LSTM1 [4][20][1024][8] bf16 (K=640: ctx|pre|h1)
#define QW2 655360u    // LSTM2 [4][24][1024][8] bf16 (K=768: h1|ctx|h2)
#define HP5 1441792u   // ac_W [64][160][8] bf16 (K=512)
// float offsets:
#define WS_ATTWT 761856u
#define WS_PW1T  816128u
#define WS_PW2T  836608u
#define WS_PRE2  869376u   // [200][32][128] fp32
#define WS_MEMH  1688576u  // memory bf16
#define WS_AVTH  2507776u  // att_V^T bf16

// dynamic-LDS float offsets
#define L_XS   0
#define L_H1   768
#define L_C1   1024
#define L_H2   1280
#define L_C2   1536
#define L_CTX  1792
#define L_AL   2048
#define L_PS   2248
#define L_ES   2448
#define L_P4   2656
#define L_QS   6752
#define L_GS   6880
#define L_FS   7048
#define L_WF   8648
#define L_PR   8816
#define L_RB   8828
#define L_B1   8848
#define L_B2   9872
#define L_AW   10896
#define DYNF   27280
#define DYNB   (DYNF*4)

__device__ __forceinline__ float sigm(float x){ return 1.f/(1.f+__expf(-x)); }
__device__ __forceinline__ float tanh_fast(float x){
  float ax = fabsf(x);
  float z = __expf(-2.f*ax);
  float r = (1.f - z)/(1.f + z);
  return (x < 0.f) ? -r : r;
}
__device__ __forceinline__ unsigned short to_bf16(float f){
  unsigned u = __float_as_uint(f);
  return (unsigned short)((u + 0x7fffu + ((u>>16)&1u)) >> 16);
}

#define FMA8S(wv, xa, xb, acc) \
  acc += __uint_as_float((wv).x<<16)*(xa).x + __uint_as_float((wv).x&0xffff0000u)*(xa).y \
       + __uint_as_float((wv).y<<16)*(xa).z + __uint_as_float((wv).y&0xffff0000u)*(xa).w \
       + __uint_as_float((wv).z<<16)*(xb).x + __uint_as_float((wv).z&0xffff0000u)*(xb).y \
       + __uint_as_float((wv).w<<16)*(xb).z + __uint_as_float((wv).w&0xffff0000u)*(xb).w;

__global__ __launch_bounds__(256) void trk(const float* __restrict__ s, float* __restrict__ d, int R, int C){
  int i = blockIdx.x*256 + threadIdx.x;
  if (i < R*C){ int r = i / C, c = i - r*C; d[c*R + r] = s[i]; }
}
__global__ __launch_bounds__(256) void pkq1c(const float* __restrict__ wih, const float* __restrict__ whh,
                                             unsigned short* __restrict__ d){
  int i = blockIdx.x*256 + threadIdx.x;
  if (i < 1024*640){
    int c = i / 640, k = i - c*640;
    float v = (k < 384) ? wih[c*384 + k] : whh[c*256 + (k-384)];
    int q = k / 160, kr = k - 160*q, kk = kr >> 3, e = kr & 7;
    d[((unsigned)((q*20 + kk)*1024 + c))*8u + e] = to_bf16(v);
  }
}
__global__ __launch_bounds__(256) void pkq2c(const float* __restrict__ wih, const float* __restrict__ whh,
                                             unsigned short* __restrict__ d){
  int i = blockIdx.x*256 + threadIdx.x;
  if (i < 1024*768){
    int c = i / 768, k = i - c*768;
    float v = (k < 512) ? wih[c*512 + k] : whh[c*256 + (k-512)];
    int q = k / 192, kr = k - 192*q, kk = kr >> 3, e = kr & 7;
    d[((unsigned)((q*24 + kk)*1024 + c))*8u + e] = to_bf16(v);
  }
}
__global__ __launch_bounds__(256) void pk8h(const float* __restrict__ s, unsigned short* __restrict__ d, int R, int C){
  int i = blockIdx.x*256 + threadIdx.x;
  if (i < R*C){ int r = i / C, c = i - r*C; d[(unsigned)(c>>3)*(unsigned)R*8u + (unsigned)r*8u + (c&7)] = to_bf16(s[i]); }
}
__global__ __launch_bounds__(256) void pkmem(const float* __restrict__ s, unsigned short* __restrict__ d, int n){
  int i = blockIdx.x*256 + threadIdx.x;
  if (i < n) d[i] = to_bf16(s[i]);
}
__global__ __launch_bounds__(256) void pkavt(const float* __restrict__ s, unsigned short* __restrict__ d){
  int i = blockIdx.x*256 + threadIdx.x;
  if (i < 128*168){ int k = i/168, a = i - k*168; d[i] = to_bf16(s[a*128 + k]); }
}

__global__ __launch_bounds__(256) void prenetk(const float* __restrict__ mels,
    const float* __restrict__ b1, const float* __restrict__ b2, float* __restrict__ ws){
  int t = blockIdx.x, tid = threadIdx.x;
  __shared__ float xS[BB*NMELS];
  __shared__ float p1S[BB*PRE1N];
  const float* W1T = ws + WS_PW1T;
  const float* W2T = ws + WS_PW2T;
  for (int i=tid;i<BB*NMELS;i+=256){
    int r = i/NMELS, k = i - r*NMELS;
    xS[i] = (t==0)?0.f : mels[r*NMELS*TMELS + k*TMELS + (2*t-1)];
  }
  __syncthreads();
  {
    float acc[BB];
    #pragma unroll
    for (int r=0;r<BB;r++) acc[r]=0.f;
    for (int k=0;k<NMELS;k++){
      float w = W1T[k*PRE1N + tid];
      #pragma unroll
      for (int r=0;r<BB;r++) acc[r] += xS[r*NMELS+k]*w;
    }
    float bb = b1[tid];
    #pragma unroll
    for (int r=0;r<BB;r++) p1S[r*PRE1N+tid] = fmaxf(acc[r]+bb, 0.f);
  }
  __syncthreads();
  if (tid < PRE2N){
    float acc[BB];
    #pragma unroll
    for (int r=0;r<BB;r++) acc[r]=0.f;
    for (int k=0;k<PRE1N;k++){
      float w = W2T[k*PRE2N + tid];
      #pragma unroll
      for (int r=0;r<BB;r++) acc[r] += p1S[r*PRE1N+k]*w;
    }
    float bb = b2[tid];
    #pragma unroll
    for (int r=0;r<BB;r++) ws[WS_PRE2 + ((unsigned)t*BB + r)*PRE2N + tid] = fmaxf(acc[r]+bb, 0.f);
  }
}

// ONE BLOCK PER BATCH. 11 barriers/step; compact code (unroll-2) + fast transcendentals.
__global__ __launch_bounds__(BLK) void decoder(
    const float* __restrict__ albih, const float* __restrict__ albhh,
    const float* __restrict__ dlbih, const float* __restrict__ dlbhh,
    const float* __restrict__ prior, const float* __restrict__ attF,
    const float* __restrict__ attWb, const float* __restrict__ attU,
    const float* __restrict__ attT, const float* __restrict__ attTb,
    const float* __restrict__ attv,
    const float* __restrict__ acb, const float* __restrict__ ws,
    float* __restrict__ out){
  extern __shared__ float sm[];
  const int b = blockIdx.x, tid = threadIdx.x;
  unsigned short* aWh = (unsigned short*)(sm + L_AW);
  const unsigned* aWu = (const unsigned*)(sm + L_AW);

  if (tid < 256){
    sm[L_H1+tid]=0.f; sm[L_C1+tid]=0.f; sm[L_H2+tid]=0.f; sm[L_C2+tid]=0.f; sm[L_CTX+tid]=0.f;
    sm[L_XS+tid]=0.f;
    sm[L_XS+384+tid]=0.f;
  }
  if (tid >= 256 && tid < 384) sm[L_XS+tid] = ws[WS_PRE2 + ((unsigned)0*BB + b)*PRE2N + (tid-256)];
  if (tid < TENC) sm[L_AL+tid] = (tid==0)?1.f:0.f;
  sm[L_B1+tid] = albih[tid] + albhh[tid];
  sm[L_B2+tid] = dlbih[tid] + dlbhh[tid];
  if (tid < SF*SK) sm[L_WF+tid] = attF[tid];
  if (tid < PL)    sm[L_PR+tid] = prior[tid];
  for (int i = tid; i < 32768; i += BLK) aWh[i] = to_bf16(ws[WS_ATTWT + i]);
  __syncthreads();

  const unsigned short* hw = (const unsigned short*)ws;
  const unsigned short* Q1 = hw + QW1;
  const unsigned short* Q2 = hw + QW2;
  const unsigned short* P5 = hw + HP5;
  const unsigned* memh = (const unsigned*)(ws + WS_MEMH);
  const unsigned short* avth = (const unsigned short*)(ws + WS_AVTH);
  const int q = tid >> 8, c0 = tid & 255;

  for (int t = 0; t < STEPS; ++t){
    // 2. LSTM1 partials
    {
      const float* xq = sm + L_XS + 160*q;
      const unsigned short* Wq = Q1 + (unsigned)q*163840u;
      float a0=0.f, a1=0.f, a2=0.f, a3=0.f;
      #pragma unroll 2
      for (int kk = 0; kk < 20; kk++){
        float4 xa = *(const float4*)(xq + 8*kk);
        float4 xb = *(const float4*)(xq + 8*kk + 4);
        const unsigned short* wr = Wq + (unsigned)kk*8192u + c0*8u;
        uint4 w0 = *(const uint4*)(wr);
        uint4 w1 = *(const uint4*)(wr + 2048);
        uint4 w2 = *(const uint4*)(wr + 4096);
        uint4 w3 = *(const uint4*)(wr + 6144);
        FMA8S(w0, xa, xb, a0)
        FMA8S(w1, xa, xb, a1)
        FMA8S(w2, xa, xb, a2)
        FMA8S(w3, xa, xb, a3)
      }
      sm[L_P4 + q*1024 + c0      ] = a0;
      sm[L_P4 + q*1024 + c0 + 256] = a1;
      sm[L_P4 + q*1024 + c0 + 512] = a2;
      sm[L_P4 + q*1024 + c0 + 768] = a3;
    }
    __syncthreads();
    // 3. LSTM1 gates + state update (fast transcendentals)
    if (tid < 256){
      float g[4];
      #pragma unroll
      for (int gg2 = 0; gg2 < 4; gg2++){
        int col = gg2*256 + tid;
        g[gg2] = sm[L_B1+col] + sm[L_P4+col] + sm[L_P4+1024+col] + sm[L_P4+2048+col] + sm[L_P4+3072+col];
      }
      float c = sigm(g[1])*sm[L_C1+tid] + sigm(g[0])*tanh_fast(g[2]);
      sm[L_C1+tid] = c;
      sm[L_H1+tid] = sigm(g[3])*tanh_fast(c);
    }
    __syncthreads();
    // 4. q-partials || convs || proj(t-1)
    if (tid < 512){
      const int quarter = tid >> 7, a = tid & 127;
      const int sel = a & 1, au = a >> 1;
      float s = 0.f;
      for (int k = 64*quarter; k < 64*quarter+64; k++){
        unsigned u = aWu[k*64 + au];
        float wv = __uint_as_float(sel ? (u & 0xffff0000u) : (u << 16));
        s += sm[L_H1+k]*wv;
      }
      sm[L_P4 + tid] = s;
    } else if (tid < 512+TENC){
      const int pos = tid - 512;
      float s = 0.f;
      #pragma unroll
      for (int jj = 0; jj < PL; jj++){ int qq = pos - jj; if (qq >= 0) s += sm[L_PR+jj]*sm[L_AL+qq]; }
      sm[L_PS+pos] = __logf(fmaxf(s, 1e-6f));
      #pragma unroll
      for (int c = 0; c < SF; c++){
        float s2 = 0.f;
        #pragma unroll
        for (int k = 0; k < SK; k++){ int qq = pos + k - 10; if (qq>=0 && qq<TENC) s2 += sm[L_WF+c*SK+k]*sm[L_AL+qq]; }
        sm[L_FS + c*TENC + pos] = s2;
      }
    } else if (tid < 872){
      if (t >= 1){
        const int col = tid - 712;
        float a0=0.f, a1=0.f;
        #pragma unroll 2
        for (int kk = 0; kk < 64; kk += 2){
          const float* xp0 = (kk   < 32) ? (sm + L_H2 + 8*kk)     : (sm + L_CTX + 8*kk - 256);
          const float* xp1 = (kk+1 < 32) ? (sm + L_H2 + 8*(kk+1)) : (sm + L_CTX + 8*(kk+1) - 256);
          uint4 w0 = *(const uint4*)(P5 + (unsigned)(kk  )*1280u + col*8u);
          uint4 w1 = *(const uint4*)(P5 + (unsigned)(kk+1)*1280u + col*8u);
          FMA8S(w0, *(const float4*)xp0, *(const float4*)(xp0+4), a0)
          FMA8S(w1, *(const float4*)xp1, *(const float4*)(xp1+4), a1)
        }
        const int m = col >> 1, r = col & 1;
        out[(unsigned)b*NMELS*TMELS + m*TMELS + 2*(t-1) + r] = a0+a1 + acb[col];
      }
    }
    __syncthreads();
    // 5. q = tanh
    if (tid < AD) sm[L_QS+tid] = tanh_fast(attWb[tid] + sm[L_P4+tid] + sm[L_P4+128+tid] + sm[L_P4+256+tid] + sm[L_P4+384+tid]);
    __syncthreads();
    // 6. G = attV @ q
    if (tid < DF*DK){
      float a = 0.f;
      for (int k = 0; k < AD; k++) a += sm[L_QS+k]*__uint_as_float(((unsigned)avth[k*(DF*DK)+tid])<<16);
      sm[L_GS+tid] = a;
    }
    __syncthreads();
    // 7. e[pos] (4 threads/pos)
    if (tid < 4*TENC){
      const int pos = tid >> 2, qr = tid & 3;
      float g[DF];
      #pragma unroll
      for (int c=0;c<DF;c++){
        float s=0.f;
        #pragma unroll
        for (int k=0;k<DK;k++){
          int q2 = pos + k - 10;
          if (q2>=0 && q2<TENC) s += sm[L_AL+q2]*sm[L_GS+c*DK+k];
        }
        g[c]=s;
      }
      float fv[SF];
      #pragma unroll
      for (int s2=0;s2<SF;s2++) fv[s2] = sm[L_FS + s2*TENC + pos];
      float pp = 0.f;
      for (int h = qr*32; h < qr*32+32; h++){
        float u = attTb[h];
        #pragma unroll
        for (int s2=0;s2<SF;s2++) u += attU[h*SF+s2]*fv[s2];
        #pragma unroll
        for (int c=0;c<DF;c++) u += attT[h*DF+c]*g[c];
        pp += attv[h]*tanh_fast(u);
      }
      pp += __shfl_xor(pp,1);
      pp += __shfl_xor(pp,2);
      if (qr==0) sm[L_ES+pos] = pp + sm[L_PS+pos];
    }
    __syncthreads();
    // 8. softmax over 200 — single wave
    if (tid < 64){
      float v0 = sm[L_ES+tid], v1 = sm[L_ES+64+tid], v2 = sm[L_ES+128+tid];
      float v3 = (tid < 8) ? sm[L_ES+192+tid] : -3.0e38f;
      float mx = fmaxf(fmaxf(v0,v1), fmaxf(v2,v3));
      for (int o=1;o<64;o<<=1) mx = fmaxf(mx, __shfl_xor(mx,o));
      float e0 = __expf(v0-mx), e1 = __expf(v1-mx), e2 = __expf(v2-mx);
      float e3 = (tid < 8) ? __expf(v3-mx) : 0.f;
      float sv = ((e0+e1)+(e2+e3));
      for (int o=1;o<64;o<<=1) sv += __shfl_xor(sv,o);
      float inv = 1.f/sv;
      float a0 = e0*inv, a1 = e1*inv, a2 = e2*inv;
      sm[L_AL+tid] = a0; sm[L_AL+64+tid] = a1; sm[L_AL+128+tid] = a2;
      unsigned ob = 1024000u + (unsigned)b*TENC*STEPS + (unsigned)t;
      out[ob + (unsigned)tid*STEPS]       = a0;
      out[ob + (unsigned)(64+tid)*STEPS]  = a1;
      out[ob + (unsigned)(128+tid)*STEPS] = a2;
      if (tid < 8){
        float a3 = e3*inv;
        sm[L_AL+192+tid] = a3;
        out[ob + (unsigned)(192+tid)*STEPS] = a3;
      }
    }
    __syncthreads();
    // 9. ctx partials (bf16 memory, cached)
    {
      const int grp2 = tid >> 7, jp = tid & 127;
      const unsigned base = ((unsigned)b*TENC)*128u + jp;
      float a0 = 0.f, a1 = 0.f;
      for (int p = grp2*25; p < grp2*25+25; p++){
        unsigned u = memh[base + (unsigned)p*128u];
        float al = sm[L_AL+p];
        a0 += al*__uint_as_float(u << 16);
        a1 += al*__uint_as_float(u & 0xffff0000u);
      }
      sm[L_P4 + grp2*256 + 2*jp    ] = a0;
      sm[L_P4 + grp2*256 + 2*jp + 1] = a1;
    }
    __syncthreads();
    // 9b. ctx reduce + build xS2 = [h1 | ctx | h2]
    if (tid < 256){
      float c = 0.f;
      #pragma unroll
      for (int g2 = 0; g2 < 8; g2++) c += sm[L_P4 + g2*256 + tid];
      sm[L_CTX+tid] = c;
      sm[L_XS+256+tid] = c;
    } else if (tid < 512){
      sm[L_XS + (tid-256)] = sm[L_H1 + (tid-256)];
    } else if (tid < 768){
      sm[L_XS + tid] = sm[L_H2 + (tid-512)];
    }
    __syncthreads();
    // 10. LSTM2 partials
    {
      const float* xq = sm + L_XS + 192*q;
      const unsigned short* Wq = Q2 + (unsigned)q*196608u;
      float a0=0.f, a1=0.f, a2=0.f, a3=0.f;
      #pragma unroll 2
      for (int kk = 0; kk < 24; kk++){
        float4 xa = *(const float4*)(xq + 8*kk);
        float4 xb = *(const float4*)(xq + 8*kk + 4);
        const unsigned short* wr = Wq + (unsigned)kk*8192u + c0*8u;
        uint4 w0 = *(const uint4*)(wr);
        uint4 w1 = *(const uint4*)(wr + 2048);
        uint4 w2 = *(const uint4*)(wr + 4096);
        uint4 w3 = *(const uint4*)(wr + 6144);
        FMA8S(w0, xa, xb, a0)
        FMA8S(w1, xa, xb, a1)
        FMA8S(w2, xa, xb, a2)
        FMA8S(w3, xa, xb, a3)
      }
      sm[L_P4 + q*1024 + c0      ] = a0;
      sm[L_P4 + q*1024 + c0 + 256] = a1;
      sm[L_P4 + q*1024 + c0 + 512] = a2;
      sm[L_P4 + q*1024 + c0 + 768] = a3;
    }
    __syncthreads();
    // 11. LSTM2 update || build xS1(t+1) || prefetch pre(t+1)
    if (tid < 256){
      float g[4];
      #pragma unroll
      for (int gg2 = 0; gg2 < 4; gg2++){
        int col = gg2*256 + tid;
        g[gg2] = sm[L_B2+col] + sm[L_P4+col] + sm[L_P4+1024+col] + sm[L_P4+2048+col] + sm[L_P4+3072+col];
      }
      float c = sigm(g[1])*sm[L_C2+tid] + sigm(g[0])*tanh_fast(g[2]);
      sm[L_C2+tid] = c;
      sm[L_H2+tid] = sigm(g[3])*tanh_fast(c);
    } else if (tid < 384){
      if (t+1 < STEPS)
        sm[L_XS+tid] = __builtin_nontemporal_load(&ws[WS_PRE2 + ((unsigned)(t+1)*BB + b)*PRE2N + (tid-256)]);
    } else if (tid < 640){
      sm[L_XS+tid] = sm[L_H1 + (tid-384)];
    } else if (tid < 896){
      sm[L_XS + (tid-640)] = sm[L_CTX + (tid-640)];
    }
    __syncthreads();
  }
  // epilogue: proj for t = STEPS-1
  if (tid < 160){
    const int col = tid;
    float a0=0.f, a1=0.f;
    #pragma unroll 2
    for (int kk = 0; kk < 64; kk += 2){
      const float* xp0 = (kk   < 32) ? (sm + L_H2 + 8*kk)     : (sm + L_CTX + 8*kk - 256);
      const float* xp1 = (kk+1 < 32) ? (sm + L_H2 + 8*(kk+1)) : (sm + L_CTX + 8*(kk+1) - 256);
      uint4 w0 = *(const uint4*)(P5 + (unsigned)(kk  )*1280u + col*8u);
      uint4 w1 = *(const uint4*)(P5 + (unsigned)(kk+1)*1280u + col*8u);
      FMA8S(w0, *(const float4*)xp0, *(const float4*)(xp0+4), a0)
      FMA8S(w1, *(const float4*)xp1, *(const float4*)(xp1+4), a1)
    }
    const int m = col >> 1, r = col & 1;
    out[(unsigned)b*NMELS*TMELS + m*TMELS + 2*(STEPS-1) + r] = a0+a1 + acb[col];
  }
}

extern "C" void kernel_launch(void* const* d_in, const int* in_sizes, int n_in,
                              void* d_out, int out_size, void* d_ws, size_t ws_size,
                              hipStream_t stream) {
  (void)in_sizes; (void)n_in; (void)out_size; (void)ws_size;
  const float* mels   = (const float*)d_in[0];
  const float* memory = (const float*)d_in[1];
  const float* pre_W1 = (const float*)d_in[2];
  const float* pre_b1 = (const float*)d_in[3];
  const float* pre_W2 = (const float*)d_in[4];
  const float* pre_b2 = (const float*)d_in[5];
  const float* al_Wih = (const float*)d_in[6];
  const float* al_Whh = (const float*)d_in[7];
  const float* al_bih = (const float*)d_in[8];
  const float* al_bhh = (const float*)d_in[9];
  const float* att_W  = (const float*)d_in[10];
  const float* att_Wb = (const float*)d_in[11];
  const float* att_V  = (const float*)d_in[12];
  const float* att_F  = (const float*)d_in[13];
  const float* att_U  = (const float*)d_in[14];
  const float* att_T  = (const float*)d_in[15];
  const float* att_Tb = (const float*)d_in[16];
  const float* att_v  = (const float*)d_in[17];
  const float* prior  = (const float*)d_in[18];
  const float* dl_Wih = (const float*)d_in[19];
  const float* dl_Whh = (const float*)d_in[20];
  const float* dl_bih = (const float*)d_in[21];
  const float* dl_bhh = (const float*)d_in[22];
  const float* ac_W   = (const float*)d_in[23];
  const float* ac_b   = (const float*)d_in[24];
  float* ws  = (float*)d_ws;
  unsigned short* hw = (unsigned short*)d_ws;
  float* out = (float*)d_out;

  hipFuncSetAttribute((const void*)decoder, hipFuncAttributeMaxDynamicSharedMemorySize, DYNB);

  auto TR = [&](const float* src, unsigned off, int R, int C){
    int n = R*C;
    trk<<<dim3((n+255)/256), dim3(256), 0, stream>>>(src, ws + off, R, C);
  };
  pkq1c<<<dim3((1024*640+255)/256), dim3(256), 0, stream>>>(al_Wih, al_Whh, hw + QW1);
  pkq2c<<<dim3((1024*768+255)/256), dim3(256), 0, stream>>>(dl_Wih, dl_Whh, hw + QW2);
  pk8h<<<dim3((160*512+255)/256), dim3(256), 0, stream>>>(ac_W, hw + HP5, 160, 512);
  TR(att_W,  WS_ATTWT, 128, 256);
  TR(pre_W1, WS_PW1T,  256, 80);
  TR(pre_W2, WS_PW2T,  128, 256);
  {
    int n = BB*TENC*MEM;
    pkmem<<<dim3((n+255)/256), dim3(256), 0, stream>>>(memory, (unsigned short*)(ws + WS_MEMH), n);
  }
  pkavt<<<dim3((128*168+255)/256), dim3(256), 0, stream>>>(att_V, (unsigned short*)(ws + WS_AVTH));

  prenetk<<<dim3(STEPS), dim3(256), 0, stream>>>(mels, pre_b1, pre_b2, ws);

  decoder<<<dim3(BB), dim3(BLK), DYNB, stream>>>(
      al_bih, al_bhh, dl_bih, dl_bhh, prior, att_F,
      att_Wb, att_U, att_T, att_Tb, att_v,
      ac_b, ws, out);
}

// Round 26
// 21055.966 us; speedup vs baseline: 1.1162x; 1.1162x over previous
//
#include <hip/hip_runtime.h>
#include <math.h>

#define BB 32
#define TENC 200
#define NMELS 80
#define TMELS 400
#define STEPS 200
#define MEM 256
#define PRE1N 256
#define PRE2N 128
#define AD 128
#define DK 21
#define DF 8
#define SK 21
#define SF 8
#define PL 11
#define BLK 1024

// ushort offsets (kk-major quarter packs, f16):
#define QW1 0u         // LSTM1 [4][20][1024][8] (K=640: ctx|pre|h1)
#define QW2 655360u    // LSTM2 [4][24][1024][8] (K=768: h1|ctx|h2)
#define HP5 1441792u   // ac_W [64][160][8] (K=512: h2|ctx)
// float offsets:
#define WS_ATTWT 761856u   // att_W^T fp32 [256][128]
#define WS_PW1T  816128u
#define WS_PW2T  836608u
#define WS_PRE2  869376u   // [200][32][128] fp32
#define WS_MEMH  1688576u  // memory f16
#define WS_AVTH  2507776u  // att_V^T f16

// dynamic-LDS float offsets (ushort regions sized as count/2 floats!)
#define L_C1   0      // 256 f
#define L_C2   256    // 256 f
#define L_AL   512    // 200 f
#define L_PS   712    // 200 f
#define L_ES   912    // 208 f
#define L_QS   1120   // 128 f
#define L_GS   1248   // 168 f
#define L_WF   1416   // 168 f
#define L_PR   1584   // 16 f
#define L_B1   1600   // 1024 f
#define L_B2   2624   // 1024 f
#define L_FS   3648   // 1600 f
#define L_P4   5248   // 4096 f
#define L_AW   9344   // 16512 uints = 16512 f  -> ends 25856
#define L_XB1  25856  // ushort[768] = 384 f    -> ends 26240
#define L_XB2  26240  // ushort[768] = 384 f    -> ends 26624
#define L_H1B  26624  // ushort[256] = 128 f    -> ends 26752
#define L_H2B  26752  // ushort[256] = 128 f    -> ends 26880
#define DYNF   26880
#define DYNB   (DYNF*4)

typedef _Float16 h2v __attribute__((ext_vector_type(2)));

__device__ __forceinline__ float sigm(float x){ return 1.f/(1.f+__expf(-x)); }
__device__ __forceinline__ float tanh_fast(float x){
  float ax = fabsf(x);
  float z = __expf(-2.f*ax);
  float r = (1.f - z)/(1.f + z);
  return (x < 0.f) ? -r : r;
}
__device__ __forceinline__ unsigned short to_f16(float f){
  _Float16 h = (_Float16)f;
  return __builtin_bit_cast(unsigned short, h);
}
__device__ __forceinline__ float f16tof(unsigned short h){
  return (float)__builtin_bit_cast(_Float16, h);
}
__device__ __forceinline__ float dot2(unsigned w, unsigned x, float acc){
  return __builtin_amdgcn_fdot2(__builtin_bit_cast(h2v, w), __builtin_bit_cast(h2v, x), acc, false);
}
#define DOT8(wv, xv, acc) \
  acc = dot2((wv).x, (xv).x, acc); \
  acc = dot2((wv).y, (xv).y, acc); \
  acc = dot2((wv).z, (xv).z, acc); \
  acc = dot2((wv).w, (xv).w, acc);

__global__ __launch_bounds__(256) void trk(const float* __restrict__ s, float* __restrict__ d, int R, int C){
  int i = blockIdx.x*256 + threadIdx.x;
  if (i < R*C){ int r = i / C, c = i - r*C; d[c*R + r] = s[i]; }
}
__global__ __launch_bounds__(256) void pkq1c(const float* __restrict__ wih, const float* __restrict__ whh,
                                             unsigned short* __restrict__ d){
  int i = blockIdx.x*256 + threadIdx.x;
  if (i < 1024*640){
    int c = i / 640, k = i - c*640;
    float v = (k < 384) ? wih[c*384 + k] : whh[c*256 + (k-384)];
    int q = k / 160, kr = k - 160*q, kk = kr >> 3, e = kr & 7;
    d[((unsigned)((q*20 + kk)*1024 + c))*8u + e] = to_f16(v);
  }
}
__global__ __launch_bounds__(256) void pkq2c(const float* __restrict__ wih, const float* __restrict__ whh,
                                             unsigned short* __restrict__ d){
  int i = blockIdx.x*256 + threadIdx.x;
  if (i < 1024*768){
    int c = i / 768, k = i - c*768;
    float v = (k < 512) ? wih[c*512 + k] : whh[c*256 + (k-512)];
    int q = k / 192, kr = k - 192*q, kk = kr >> 3, e = kr & 7;
    d[((unsigned)((q*24 + kk)*1024 + c))*8u + e] = to_f16(v);
  }
}
__global__ __launch_bounds__(256) void pk8h(const float* __restrict__ s, unsigned short* __restrict__ d, int R, int C){
  int i = blockIdx.x*256 + threadIdx.x;
  if (i < R*C){ int r = i / C, c = i - r*C; d[(unsigned)(c>>3)*(unsigned)R*8u + (unsigned)r*8u + (c&7)] = to_f16(s[i]); }
}
__global__ __launch_bounds__(256) void pkmem(const float* __restrict__ s, unsigned short* __restrict__ d, int n){
  int i = blockIdx.x*256 + threadIdx.x;
  if (i < n) d[i] = to_f16(s[i]);
}
__global__ __launch_bounds__(256) void pkavt(const float* __restrict__ s, unsigned short* __restrict__ d){
  int i = blockIdx.x*256 + threadIdx.x;
  if (i < 128*168){ int k = i/168, a = i - k*168; d[i] = to_f16(s[a*128 + k]); }
}

__global__ __launch_bounds__(256) void prenetk(const float* __restrict__ mels,
    const float* __restrict__ b1, const float* __restrict__ b2, float* __restrict__ ws){
  int t = blockIdx.x, tid = threadIdx.x;
  __shared__ float xS[BB*NMELS];
  __shared__ float p1S[BB*PRE1N];
  const float* W1T = ws + WS_PW1T;
  const float* W2T = ws + WS_PW2T;
  for (int i=tid;i<BB*NMELS;i+=256){
    int r = i/NMELS, k = i - r*NMELS;
    xS[i] = (t==0)?0.f : mels[r*NMELS*TMELS + k*TMELS + (2*t-1)];
  }
  __syncthreads();
  {
    float acc[BB];
    #pragma unroll
    for (int r=0;r<BB;r++) acc[r]=0.f;
    for (int k=0;k<NMELS;k++){
      float w = W1T[k*PRE1N + tid];
      #pragma unroll
      for (int r=0;r<BB;r++) acc[r] += xS[r*NMELS+k]*w;
    }
    float bb = b1[tid];
    #pragma unroll
    for (int r=0;r<BB;r++) p1S[r*PRE1N+tid] = fmaxf(acc[r]+bb, 0.f);
  }
  __syncthreads();
  if (tid < PRE2N){
    float acc[BB];
    #pragma unroll
    for (int r=0;r<BB;r++) acc[r]=0.f;
    for (int k=0;k<PRE1N;k++){
      float w = W2T[k*PRE2N + tid];
      #pragma unroll
      for (int r=0;r<BB;r++) acc[r] += p1S[r*PRE1N+k]*w;
    }
    float bb = b2[tid];
    #pragma unroll
    for (int r=0;r<BB;r++) ws[WS_PRE2 + ((unsigned)t*BB + r)*PRE2N + tid] = fmaxf(acc[r]+bb, 0.f);
  }
}

// ONE BLOCK PER BATCH. f16 dot2 GEMVs; packed-f16 activations; 11 barriers/step.
__global__ __launch_bounds__(BLK) void decoder(
    const float* __restrict__ albih, const float* __restrict__ albhh,
    const float* __restrict__ dlbih, const float* __restrict__ dlbhh,
    const float* __restrict__ prior, const float* __restrict__ attF,
    const float* __restrict__ attWb, const float* __restrict__ attU,
    const float* __restrict__ attT, const float* __restrict__ attTb,
    const float* __restrict__ attv,
    const float* __restrict__ acb, const float* __restrict__ ws,
    float* __restrict__ out){
  extern __shared__ float sm[];
  const int b = blockIdx.x, tid = threadIdx.x;
  unsigned* aW2u = (unsigned*)(sm + L_AW);
  unsigned short* xb1 = (unsigned short*)(sm + L_XB1);
  unsigned short* xb2 = (unsigned short*)(sm + L_XB2);
  unsigned short* h1b = (unsigned short*)(sm + L_H1B);
  unsigned short* h2b = (unsigned short*)(sm + L_H2B);
  const unsigned* h1p = (const unsigned*)(sm + L_H1B);

  // ---- one-time init ----
  if (tid < 256){
    sm[L_C1+tid]=0.f; sm[L_C2+tid]=0.f;
    xb1[tid]=0; xb1[384+tid]=0;      // ctx, h1 parts of xS1(0)
    h2b[tid]=0;
  }
  if (tid >= 256 && tid < 384) xb1[tid] = to_f16(ws[WS_PRE2 + (unsigned)b*PRE2N + (tid-256)]);
  if (tid < TENC) sm[L_AL+tid] = (tid==0)?1.f:0.f;
  sm[L_B1+tid] = albih[tid] + albhh[tid];
  sm[L_B2+tid] = dlbih[tid] + dlbhh[tid];
  if (tid < SF*SK) sm[L_WF+tid] = attF[tid];
  if (tid < PL)    sm[L_PR+tid] = prior[tid];
  for (int i = tid; i < 16384; i += BLK){
    int a = i >> 7, kk = i & 127;
    unsigned lo = to_f16(ws[WS_ATTWT + (unsigned)(2*kk)*128u + a]);
    unsigned hi = to_f16(ws[WS_ATTWT + (unsigned)(2*kk+1)*128u + a]);
    aW2u[a*129 + kk] = lo | (hi << 16);
  }
  __syncthreads();

  const unsigned short* hw = (const unsigned short*)ws;
  const unsigned short* Q1 = hw + QW1;
  const unsigned short* Q2 = hw + QW2;
  const unsigned short* P5 = hw + HP5;
  const unsigned* memh = (const unsigned*)(ws + WS_MEMH);
  const unsigned short* avth = (const unsigned short*)(ws + WS_AVTH);
  const int q = tid >> 8, c0 = tid & 255;

  for (int t = 0; t < STEPS; ++t){
    // 2. LSTM1 partials: quarter q, cols c0+256j, dot2
    {
      const uint4* xq = (const uint4*)(xb1 + 160*q);
      const unsigned short* Wq = Q1 + (unsigned)q*163840u;
      float a0=0.f, a1=0.f, a2=0.f, a3=0.f;
      #pragma unroll 2
      for (int kk = 0; kk < 20; kk++){
        uint4 xv = xq[kk];
        const unsigned short* wr = Wq + (unsigned)kk*8192u + c0*8u;
        uint4 w0 = *(const uint4*)(wr);
        uint4 w1 = *(const uint4*)(wr + 2048);
        uint4 w2 = *(const uint4*)(wr + 4096);
        uint4 w3 = *(const uint4*)(wr + 6144);
        DOT8(w0, xv, a0)
        DOT8(w1, xv, a1)
        DOT8(w2, xv, a2)
        DOT8(w3, xv, a3)
      }
      sm[L_P4 + q*1024 + c0      ] = a0;
      sm[L_P4 + q*1024 + c0 + 256] = a1;
      sm[L_P4 + q*1024 + c0 + 512] = a2;
      sm[L_P4 + q*1024 + c0 + 768] = a3;
    }
    __syncthreads();
    // 3. LSTM1 gates + state update -> h1b (f16)
    if (tid < 256){
      float g[4];
      #pragma unroll
      for (int gg2 = 0; gg2 < 4; gg2++){
        int col = gg2*256 + tid;
        g[gg2] = sm[L_B1+col] + sm[L_P4+col] + sm[L_P4+1024+col] + sm[L_P4+2048+col] + sm[L_P4+3072+col];
      }
      float c = sigm(g[1])*sm[L_C1+tid] + sigm(g[0])*tanh_fast(g[2]);
      sm[L_C1+tid] = c;
      h1b[tid] = to_f16(sigm(g[3])*tanh_fast(c));
    }
    __syncthreads();
    // 4. q-partials via dot2 (tid<512) || convs (512..711) || proj(t-1) via dot2 (712..871)
    if (tid < 512){
      const int quarter = tid >> 7, a = tid & 127;
      const unsigned* wrow = aW2u + a*129;
      float s = 0.f;
      #pragma unroll 4
      for (int kk = 32*quarter; kk < 32*quarter+32; kk++)
        s = dot2(wrow[kk], h1p[kk], s);
      sm[L_P4 + tid] = s;
    } else if (tid < 512+TENC){
      const int pos = tid - 512;
      float s = 0.f;
      #pragma unroll
      for (int jj = 0; jj < PL; jj++){ int qq = pos - jj; if (qq >= 0) s += sm[L_PR+jj]*sm[L_AL+qq]; }
      sm[L_PS+pos] = __logf(fmaxf(s, 1e-6f));
      #pragma unroll
      for (int c = 0; c < SF; c++){
        float s2 = 0.f;
        #pragma unroll
        for (int k = 0; k < SK; k++){ int qq = pos + k - 10; if (qq>=0 && qq<TENC) s2 += sm[L_WF+c*SK+k]*sm[L_AL+qq]; }
        sm[L_FS + c*TENC + pos] = s2;
      }
    } else if (tid < 872){
      if (t >= 1){
        const int col = tid - 712;
        const uint4* xv2  = (const uint4*)xb2;   // ctx(t-1) at uint4 idx 32..63
        const uint4* h2v4 = (const uint4*)h2b;   // h2(t-1), fresh from phase 11
        float a0=0.f, a1=0.f;
        #pragma unroll 2
        for (int kk = 0; kk < 64; kk += 2){
          uint4 x0 = (kk   < 32) ? h2v4[kk]   : xv2[kk];
          uint4 x1 = (kk+1 < 32) ? h2v4[kk+1] : xv2[kk+1];
          uint4 w0 = *(const uint4*)(P5 + (unsigned)(kk  )*1280u + col*8u);
          uint4 w1 = *(const uint4*)(P5 + (unsigned)(kk+1)*1280u + col*8u);
          DOT8(w0, x0, a0)
          DOT8(w1, x1, a1)
        }
        const int m = col >> 1, r = col & 1;
        out[(unsigned)b*NMELS*TMELS + m*TMELS + 2*(t-1) + r] = a0+a1 + acb[col];
      }
    }
    __syncthreads();
    // 5. q = tanh
    if (tid < AD) sm[L_QS+tid] = tanh_fast(attWb[tid] + sm[L_P4+tid] + sm[L_P4+128+tid] + sm[L_P4+256+tid] + sm[L_P4+384+tid]);
    __syncthreads();
    // 6. G = attV @ q (f16 decode)
    if (tid < DF*DK){
      float a = 0.f;
      for (int k = 0; k < AD; k++) a += sm[L_QS+k]*f16tof(avth[k*(DF*DK)+tid]);
      sm[L_GS+tid] = a;
    }
    __syncthreads();
    // 7. e[pos] (4 threads/pos)
    if (tid < 4*TENC){
      const int pos = tid >> 2, qr = tid & 3;
      float g[DF];
      #pragma unroll
      for (int c=0;c<DF;c++){
        float s=0.f;
        #pragma unroll
        for (int k=0;k<DK;k++){
          int q2 = pos + k - 10;
          if (q2>=0 && q2<TENC) s += sm[L_AL+q2]*sm[L_GS+c*DK+k];
        }
        g[c]=s;
      }
      float fv[SF];
      #pragma unroll
      for (int s2=0;s2<SF;s2++) fv[s2] = sm[L_FS + s2*TENC + pos];
      float pp = 0.f;
      for (int h = qr*32; h < qr*32+32; h++){
        float u = attTb[h];
        #pragma unroll
        for (int s2=0;s2<SF;s2++) u += attU[h*SF+s2]*fv[s2];
        #pragma unroll
        for (int c=0;c<DF;c++) u += attT[h*DF+c]*g[c];
        pp += attv[h]*tanh_fast(u);
      }
      pp += __shfl_xor(pp,1);
      pp += __shfl_xor(pp,2);
      if (qr==0) sm[L_ES+pos] = pp + sm[L_PS+pos];
    }
    __syncthreads();
    // 8. softmax over 200 — single wave
    if (tid < 64){
      float v0 = sm[L_ES+tid], v1 = sm[L_ES+64+tid], v2 = sm[L_ES+128+tid];
      float v3 = (tid < 8) ? sm[L_ES+192+tid] : -3.0e38f;
      float mx = fmaxf(fmaxf(v0,v1), fmaxf(v2,v3));
      for (int o=1;o<64;o<<=1) mx = fmaxf(mx, __shfl_xor(mx,o));
      float e0 = __expf(v0-mx), e1 = __expf(v1-mx), e2 = __expf(v2-mx);
      float e3 = (tid < 8) ? __expf(v3-mx) : 0.f;
      float sv = ((e0+e1)+(e2+e3));
      for (int o=1;o<64;o<<=1) sv += __shfl_xor(sv,o);
      float inv = 1.f/sv;
      float a0 = e0*inv, a1 = e1*inv, a2 = e2*inv;
      sm[L_AL+tid] = a0; sm[L_AL+64+tid] = a1; sm[L_AL+128+tid] = a2;
      unsigned ob = 1024000u + (unsigned)b*TENC*STEPS + (unsigned)t;
      out[ob + (unsigned)tid*STEPS]       = a0;
      out[ob + (unsigned)(64+tid)*STEPS]  = a1;
      out[ob + (unsigned)(128+tid)*STEPS] = a2;
      if (tid < 8){
        float a3 = e3*inv;
        sm[L_AL+192+tid] = a3;
        out[ob + (unsigned)(192+tid)*STEPS] = a3;
      }
    }
    __syncthreads();
    // 9. ctx partials (f16 memory, cached)
    {
      const int grp2 = tid >> 7, jp = tid & 127;
      const unsigned base = ((unsigned)b*TENC)*128u + jp;
      float a0 = 0.f, a1 = 0.f;
      for (int p = grp2*25; p < grp2*25+25; p++){
        unsigned u = memh[base + (unsigned)p*128u];
        float al = sm[L_AL+p];
        a0 += al*f16tof((unsigned short)(u & 0xffffu));
        a1 += al*f16tof((unsigned short)(u >> 16));
      }
      sm[L_P4 + grp2*256 + 2*jp    ] = a0;
      sm[L_P4 + grp2*256 + 2*jp + 1] = a1;
    }
    __syncthreads();
    // 9b. ctx reduce + build xS2 = [h1 | ctx | h2] (packed f16; h2 = h2(t-1) for LSTM2)
    if (tid < 256){
      float c = 0.f;
      #pragma unroll
      for (int g2 = 0; g2 < 8; g2++) c += sm[L_P4 + g2*256 + tid];
      xb2[256+tid] = to_f16(c);
    } else if (tid < 512){
      xb2[tid-256] = h1b[tid-256];
    } else if (tid < 768){
      xb2[512 + (tid-512)] = h2b[tid-512];
    }
    __syncthreads();
    // 10. LSTM2 partials: quarter q, dot2
    {
      const uint4* xq = (const uint4*)(xb2 + 192*q);
      const unsigned short* Wq = Q2 + (unsigned)q*196608u;
      float a0=0.f, a1=0.f, a2=0.f, a3=0.f;
      #pragma unroll 2
      for (int kk = 0; kk < 24; kk++){
        uint4 xv = xq[kk];
        const unsigned short* wr = Wq + (unsigned)kk*8192u + c0*8u;
        uint4 w0 = *(const uint4*)(wr);
        uint4 w1 = *(const uint4*)(wr + 2048);
        uint4 w2 = *(const uint4*)(wr + 4096);
        uint4 w3 = *(const uint4*)(wr + 6144);
        DOT8(w0, xv, a0)
        DOT8(w1, xv, a1)
        DOT8(w2, xv, a2)
        DOT8(w3, xv, a3)
      }
      sm[L_P4 + q*1024 + c0      ] = a0;
      sm[L_P4 + q*1024 + c0 + 256] = a1;
      sm[L_P4 + q*1024 + c0 + 512] = a2;
      sm[L_P4 + q*1024 + c0 + 768] = a3;
    }
    __syncthreads();
    // 11. LSTM2 update -> h2b || build xS1(t+1) || prefetch pre(t+1)
    if (tid < 256){
      float g[4];
      #pragma unroll
      for (int gg2 = 0; gg2 < 4; gg2++){
        int col = gg2*256 + tid;
        g[gg2] = sm[L_B2+col] + sm[L_P4+col] + sm[L_P4+1024+col] + sm[L_P4+2048+col] + sm[L_P4+3072+col];
      }
      float c = sigm(g[1])*sm[L_C2+tid] + sigm(g[0])*tanh_fast(g[2]);
      sm[L_C2+tid] = c;
      h2b[tid] = to_f16(sigm(g[3])*tanh_fast(c));
    } else if (tid < 384){
      if (t+1 < STEPS)
        xb1[tid] = to_f16(__builtin_nontemporal_load(&ws[WS_PRE2 + ((unsigned)(t+1)*BB + b)*PRE2N + (tid-256)]));
    } else if (tid < 640){
      xb1[tid] = xb2[tid-384];                  // h1(t)
    } else if (tid < 896){
      xb1[tid-640] = xb2[256 + (tid-640)];      // ctx(t)
    }
    __syncthreads();
  }
  // epilogue: proj for t = STEPS-1 from h2b (= h2(199)) + xb2 ctx (= ctx(199))
  if (tid < 160){
    const int col = tid;
    const uint4* xv2  = (const uint4*)xb2;
    const uint4* h2v4 = (const uint4*)h2b;
    float a0=0.f, a1=0.f;
    #pragma unroll 2
    for (int kk = 0; kk < 64; kk += 2){
      uint4 x0 = (kk   < 32) ? h2v4[kk]   : xv2[kk];
      uint4 x1 = (kk+1 < 32) ? h2v4[kk+1] : xv2[kk+1];
      uint4 w0 = *(const uint4*)(P5 + (unsigned)(kk  )*1280u + col*8u);
      uint4 w1 = *(const uint4*)(P5 + (unsigned)(kk+1)*1280u + col*8u);
      DOT8(w0, x0, a0)
      DOT8(w1, x1, a1)
    }
    const int m = col >> 1, r = col & 1;
    out[(unsigned)b*NMELS*TMELS + m*TMELS + 2*(STEPS-1) + r] = a0+a1 + acb[col];
  }
}

extern "C" void kernel_launch(void* const* d_in, const int* in_sizes, int n_in,
                              void* d_out, int out_size, void* d_ws, size_t ws_size,
                              hipStream_t stream) {
  (void)in_sizes; (void)n_in; (void)out_size; (void)ws_size;
  const float* mels   = (const float*)d_in[0];
  const float* memory = (const float*)d_in[1];
  const float* pre_W1 = (const float*)d_in[2];
  const float* pre_b1 = (const float*)d_in[3];
  const float* pre_W2 = (const float*)d_in[4];
  const float* pre_b2 = (const float*)d_in[5];
  const float* al_Wih = (const float*)d_in[6];
  const float* al_Whh = (const float*)d_in[7];
  const float* al_bih = (const float*)d_in[8];
  const float* al_bhh = (const float*)d_in[9];
  const float* att_W  = (const float*)d_in[10];
  const float* att_Wb = (const float*)d_in[11];
  const float* att_V  = (const float*)d_in[12];
  const float* att_F  = (const float*)d_in[13];
  const float* att_U  = (const float*)d_in[14];
  const float* att_T  = (const float*)d_in[15];
  const float* att_Tb = (const float*)d_in[16];
  const float* att_v  = (const float*)d_in[17];
  const float* prior  = (const float*)d_in[18];
  const float* dl_Wih = (const float*)d_in[19];
  const float* dl_Whh = (const float*)d_in[20];
  const float* dl_bih = (const float*)d_in[21];
  const float* dl_bhh = (const float*)d_in[22];
  const float* ac_W   = (const float*)d_in[23];
  const float* ac_b   = (const float*)d_in[24];
  float* ws  = (float*)d_ws;
  unsigned short* hw = (unsigned short*)d_ws;
  float* out = (float*)d_out;

  hipFuncSetAttribute((const void*)decoder, hipFuncAttributeMaxDynamicSharedMemorySize, DYNB);

  auto TR = [&](const float* src, unsigned off, int R, int C){
    int n = R*C;
    trk<<<dim3((n+255)/256), dim3(256), 0, stream>>>(src, ws + off, R, C);
  };
  pkq1c<<<dim3((1024*640+255)/256), dim3(256), 0, stream>>>(al_Wih, al_Whh, hw + QW1);
  pkq2c<<<dim3((1024*768+255)/256), dim3(256), 0, stream>>>(dl_Wih, dl_Whh, hw + QW2);
  pk8h<<<dim3((160*512+255)/256), dim3(256), 0, stream>>>(ac_W, hw + HP5, 160, 512);
  TR(att_W,  WS_ATTWT, 128, 256);
  TR(pre_W1, WS_PW1T,  256, 80);
  TR(pre_W2, WS_PW2T,  128, 256);
  {
    int n = BB*TENC*MEM;
    pkmem<<<dim3((n+255)/256), dim3(256), 0, stream>>>(memory, (unsigned short*)(ws + WS_MEMH), n);
  }
  pkavt<<<dim3((128*168+255)/256), dim3(256), 0, stream>>>(att_V, (unsigned short*)(ws + WS_AVTH));

  prenetk<<<dim3(STEPS), dim3(256), 0, stream>>>(mels, pre_b1, pre_b2, ws);

  decoder<<<dim3(BB), dim3(BLK), DYNB, stream>>>(
      al_bih, al_bhh, dl_bih, dl_bhh, prior, att_F,
      att_Wb, att_U, att_T, att_Tb, att_v,
      ac_b, ws, out);
}